// Round 1
// baseline (524.957 us; speedup 1.0000x reference)
//
#include <hip/hip_runtime.h>

// Problem constants (fixed by the reference): B=512, T=1024, D=64, U=5.
#define BB 512
#define TT 1024
#define DD 64
#define UU 5

// ---------------------------------------------------------------------------
// Kernel 1: px[t][b][k] = sum_d tx[b][t][d] * kernel[d][k] + bias[k]
//   - tx is (B,T,D) f32, kernel is (D,10), bias (10,)
//   - px written in (T,B,10) layout so the scan kernel reads coalesced.
//   - block = 256 threads = 64 b-lanes x 4 t; grid = (B/64, T/4) = (8,256)
//   - kernel matrix (2.5 KB) staged in LDS; per-thread 16x float4 tx loads.
// ---------------------------------------------------------------------------
__global__ __launch_bounds__(256) void px_gemm(
    const float* __restrict__ tx,
    const float* __restrict__ kern,
    const float* __restrict__ bias,
    float* __restrict__ px) {
  __shared__ float sK[DD * 10];
  for (int i = threadIdx.x; i < DD * 10; i += 256) sK[i] = kern[i];
  __syncthreads();

  const int b = blockIdx.x * 64 + (threadIdx.x & 63);
  const int t = blockIdx.y * 4 + (threadIdx.x >> 6);

  const float4* tx4 = (const float4*)(tx + ((size_t)b * TT + t) * DD);

  float acc[10];
#pragma unroll
  for (int k = 0; k < 10; ++k) acc[k] = bias[k];

#pragma unroll
  for (int i = 0; i < 16; ++i) {
    float4 x = tx4[i];
#pragma unroll
    for (int dd = 0; dd < 4; ++dd) {
      const float xv = (&x.x)[dd];
#pragma unroll
      for (int k = 0; k < 10; ++k)
        acc[k] = fmaf(xv, sK[(i * 4 + dd) * 10 + k], acc[k]);
    }
  }

  // write 40 B per thread, lanes = consecutive b -> coalesced (8B-aligned)
  float2* o2 = (float2*)(px + ((size_t)t * BB + b) * 10);
#pragma unroll
  for (int k = 0; k < 5; ++k) o2[k] = make_float2(acc[2 * k], acc[2 * k + 1]);
}

// ---------------------------------------------------------------------------
// Kernel 2: the sequential scan over T, one thread per batch row.
//   h[5] in registers; Rf/Rh (5x5 each) in registers (uniform loads).
//   Per step: v1 = sigmoid(p1 + h@Rf); v2 = tanh(p2 + (h*v1)@Rh);
//             h  = h + v1*(v2 - h)
//   Software-prefetch next step's 40 B (5x float2) while computing.
//   Epilogue: softmax(h @ fc_w + fc_b) -> out[b][0..3] as one float4.
// ---------------------------------------------------------------------------
__global__ __launch_bounds__(64) void rnn_scan(
    const float* __restrict__ px,
    const float* __restrict__ rec,
    const float* __restrict__ fcw,
    const float* __restrict__ fcb,
    float* __restrict__ out) {
  const int b = blockIdx.x * 64 + threadIdx.x;

  float Rf[UU][UU], Rh[UU][UU];
#pragma unroll
  for (int i = 0; i < UU; ++i) {
#pragma unroll
    for (int j = 0; j < UU; ++j) {
      Rf[i][j] = rec[i * (2 * UU) + j];
      Rh[i][j] = rec[i * (2 * UU) + UU + j];
    }
  }

  float h[UU] = {0.f, 0.f, 0.f, 0.f, 0.f};

  const float2* base = (const float2*)px + (size_t)b * 5;
  const size_t st2 = (size_t)BB * 5;  // float2 stride per t step

  float2 c[5];
#pragma unroll
  for (int k = 0; k < 5; ++k) c[k] = base[k];

  for (int t = 0; t < TT; ++t) {
    // prefetch next step (clamped so last iter re-reads t, harmless)
    const int tn = (t + 1 < TT) ? (t + 1) : t;
    const float2* nb = base + (size_t)tn * st2;
    float2 n[5];
#pragma unroll
    for (int k = 0; k < 5; ++k) n[k] = nb[k];

    const float p1v[UU] = {c[0].x, c[0].y, c[1].x, c[1].y, c[2].x};
    const float p2v[UU] = {c[2].y, c[3].x, c[3].y, c[4].x, c[4].y};

    float v1[UU], hv[UU];
#pragma unroll
    for (int j = 0; j < UU; ++j) {
      float a = p1v[j];
#pragma unroll
      for (int i = 0; i < UU; ++i) a = fmaf(h[i], Rf[i][j], a);
      a = fminf(fmaxf(a, -30.f), 30.f);
      v1[j] = 1.f / (1.f + __expf(-a));
    }
#pragma unroll
    for (int i = 0; i < UU; ++i) hv[i] = h[i] * v1[i];

#pragma unroll
    for (int j = 0; j < UU; ++j) {
      float a = p2v[j];
#pragma unroll
      for (int i = 0; i < UU; ++i) a = fmaf(hv[i], Rh[i][j], a);
      a = fminf(fmaxf(a, -15.f), 15.f);
      const float e = __expf(2.f * a);
      const float v2 = (e - 1.f) / (e + 1.f);
      h[j] = fmaf(v1[j], v2 - h[j], h[j]);
    }

#pragma unroll
    for (int k = 0; k < 5; ++k) c[k] = n[k];
  }

  // fused head: logits = h @ fc_w + fc_b ; softmax over 4
  float l[4];
#pragma unroll
  for (int j = 0; j < 4; ++j) {
    float a = fcb[j];
#pragma unroll
    for (int i = 0; i < UU; ++i) a = fmaf(h[i], fcw[i * 4 + j], a);
    l[j] = a;
  }
  const float m = fmaxf(fmaxf(l[0], l[1]), fmaxf(l[2], l[3]));
  const float e0 = __expf(l[0] - m);
  const float e1 = __expf(l[1] - m);
  const float e2 = __expf(l[2] - m);
  const float e3 = __expf(l[3] - m);
  const float inv = 1.f / (e0 + e1 + e2 + e3);
  float4 o;
  o.x = e0 * inv; o.y = e1 * inv; o.z = e2 * inv; o.w = e3 * inv;
  *(float4*)(out + (size_t)b * 4) = o;
}

extern "C" void kernel_launch(void* const* d_in, const int* in_sizes, int n_in,
                              void* d_out, int out_size, void* d_ws, size_t ws_size,
                              hipStream_t stream) {
  const float* tx   = (const float*)d_in[0];
  const float* kern = (const float*)d_in[1];
  const float* rec  = (const float*)d_in[2];
  const float* bias = (const float*)d_in[3];
  const float* fcw  = (const float*)d_in[4];
  const float* fcb  = (const float*)d_in[5];
  float* out = (float*)d_out;
  float* px  = (float*)d_ws;  // needs T*B*10*4 = 20,971,520 bytes

  dim3 grid(BB / 64, TT / 4);
  px_gemm<<<grid, 256, 0, stream>>>(tx, kern, bias, px);
  rnn_scan<<<BB / 64, 64, 0, stream>>>(px, rec, fcw, fcb, out);
}